// Round 1
// baseline (700.583 us; speedup 1.0000x reference)
//
#include <hip/hip_runtime.h>
#include <hip/hip_bf16.h>
#include <math.h>

typedef __hip_bfloat16 bf16;
typedef __attribute__((ext_vector_type(8))) short short8;
typedef __attribute__((ext_vector_type(4))) float floatx4;

#define EMB   1024
#define SEQ   2048
#define BATCH 4
#define M_TOK 8192
#define HEADS 16
#define HDIM  64
#define FFDIM 4096

typedef __attribute__((address_space(3))) void lds_t;
typedef __attribute__((address_space(1))) void glob_t;

static __device__ __forceinline__ void gll16(const bf16* g, bf16* l) {
  __builtin_amdgcn_global_load_lds((const glob_t*)g, (lds_t*)l, 16, 0, 0);
}

static __device__ __forceinline__ unsigned short f2bu(float f) {
  union { __hip_bfloat16 h; unsigned short u; } cv;
  cv.h = __float2bfloat16(f);
  return cv.u;
}

static __device__ __forceinline__ float gelu_f(float x) {
  float t = tanhf(0.7978845608028654f * (x + 0.044715f * x * x * x));
  return 0.5f * x * (1.0f + t);
}

// ---- weight convert + transpose: W fp32 [Kd][Nd] -> Wt bf16 [Nd][Kd] ----
__global__ __launch_bounds__(256) void wconv_kernel(const float* __restrict__ W,
                                                    bf16* __restrict__ Wt,
                                                    int Kd, int Nd) {
  __shared__ float tile[32][33];
  int n0 = blockIdx.x * 32, k0 = blockIdx.y * 32;
  int tx = threadIdx.x & 31, ty = threadIdx.x >> 5;
  #pragma unroll
  for (int j = 0; j < 32; j += 8)
    tile[ty + j][tx] = W[(size_t)(k0 + ty + j) * Nd + n0 + tx];
  __syncthreads();
  #pragma unroll
  for (int j = 0; j < 32; j += 8)
    Wt[(size_t)(n0 + ty + j) * Kd + k0 + tx] = __float2bfloat16(tile[tx][ty + j]);
}

// ---- LayerNorm (ddof=1): fp32 [8192][1024] -> bf16 ----
__global__ __launch_bounds__(256) void ln_kernel(const float* __restrict__ x,
                                                 const float* __restrict__ sc,
                                                 const float* __restrict__ bi,
                                                 bf16* __restrict__ out) {
  int row = blockIdx.x, tid = threadIdx.x;
  const float4* xr = (const float4*)(x + (size_t)row * EMB);
  float4 v = xr[tid];
  float s  = v.x + v.y + v.z + v.w;
  float s2 = v.x * v.x + v.y * v.y + v.z * v.z + v.w * v.w;
  #pragma unroll
  for (int off = 1; off < 64; off <<= 1) {
    s  += __shfl_xor(s, off);
    s2 += __shfl_xor(s2, off);
  }
  __shared__ float red[8];
  int wv = tid >> 6;
  if ((tid & 63) == 0) { red[wv] = s; red[4 + wv] = s2; }
  __syncthreads();
  s  = red[0] + red[1] + red[2] + red[3];
  s2 = red[4] + red[5] + red[6] + red[7];
  float mean = s * (1.0f / EMB);
  float var  = (s2 - (float)EMB * mean * mean) * (1.0f / (EMB - 1));
  float rstd = rsqrtf(var + 1e-5f);
  float4 scv = ((const float4*)sc)[tid];
  float4 biv = ((const float4*)bi)[tid];
  ushort4 o;
  o.x = f2bu((v.x - mean) * rstd * scv.x + biv.x);
  o.y = f2bu((v.y - mean) * rstd * scv.y + biv.y);
  o.z = f2bu((v.z - mean) * rstd * scv.z + biv.z);
  o.w = f2bu((v.w - mean) * rstd * scv.w + biv.w);
  ((ushort4*)(out + (size_t)row * EMB))[tid] = o;
}

// ---- GEMM: C[M=8192][Nd] = A[M][Kd] * Bt[Nd][Kd]^T, m97 structure ----
// MODE 0: q scatter [b,h,s,d] with *0.125   MODE 1: k scatter [b,h,s,d]
// MODE 2: v scatter transposed [b,h,d,s]    MODE 3: fp32 out = C+bias+resid
// MODE 4: bf16 out = gelu(C+bias)           MODE 5: fp32 out = C+bias+resid
template<int Nd, int Kd, int MODE>
__global__ __launch_bounds__(256, 2) void gemm_kernel(
    const bf16* __restrict__ A, const bf16* __restrict__ Bt,
    const float* __restrict__ bias, const float* __restrict__ resid,
    void* __restrict__ outp) {
  __shared__ __align__(16) bf16 As[128 * 32];
  __shared__ __align__(16) bf16 Bs[128 * 32];
  const int m0 = blockIdx.x * 128, n0 = blockIdx.y * 128;
  const int tid = threadIdx.x;
  const int lane = tid & 63, wave = tid >> 6;
  const int lo = lane & 15, hi = lane >> 4;
  const int wr = wave >> 1, wc = wave & 1;

  floatx4 acc[4][4];
  #pragma unroll
  for (int i = 0; i < 4; i++)
    #pragma unroll
    for (int j = 0; j < 4; j++)
      #pragma unroll
      for (int r = 0; r < 4; r++) acc[i][j][r] = 0.0f;

  const bf16* Ab = A  + (size_t)m0 * Kd;
  const bf16* Bb = Bt + (size_t)n0 * Kd;

  for (int k0 = 0; k0 < Kd; k0 += 32) {
    #pragma unroll
    for (int s = 0; s < 2; ++s) {
      int c = tid + s * 256;   // chunk: row = c>>2, 16B sub-chunk = c&3
      gll16(Ab + (size_t)(c >> 2) * Kd + k0 + (c & 3) * 8, As + c * 8);
      gll16(Bb + (size_t)(c >> 2) * Kd + k0 + (c & 3) * 8, Bs + c * 8);
    }
    __syncthreads();
    short8 af[4], bfr[4];
    #pragma unroll
    for (int i = 0; i < 4; i++)
      af[i] = *(const short8*)&As[(wr * 64 + i * 16 + lo) * 32 + hi * 8];
    #pragma unroll
    for (int j = 0; j < 4; j++)
      bfr[j] = *(const short8*)&Bs[(wc * 64 + j * 16 + lo) * 32 + hi * 8];
    #pragma unroll
    for (int i = 0; i < 4; i++)
      #pragma unroll
      for (int j = 0; j < 4; j++)
        acc[i][j] = __builtin_amdgcn_mfma_f32_16x16x32_bf16(af[i], bfr[j], acc[i][j], 0, 0, 0);
    __syncthreads();
  }

  #pragma unroll
  for (int i = 0; i < 4; i++) {
    #pragma unroll
    for (int j = 0; j < 4; j++) {
      #pragma unroll
      for (int r = 0; r < 4; r++) {
        const int m = m0 + wr * 64 + i * 16 + hi * 4 + r;  // D: row=(lane>>4)*4+reg
        const int n = n0 + wc * 64 + j * 16 + lo;          //    col=lane&15
        float cv = acc[i][j][r];
        if constexpr (MODE == 0 || MODE == 1) {
          if constexpr (MODE == 0) cv *= 0.125f;  // fold softmax scale into q
          int b = m >> 11, ss = m & 2047, hh = n >> 6, d = n & 63;
          ((bf16*)outp)[((size_t)(b * HEADS + hh) * SEQ + ss) * HDIM + d] = __float2bfloat16(cv);
        } else if constexpr (MODE == 2) {
          int b = m >> 11, ss = m & 2047, hh = n >> 6, d = n & 63;
          ((bf16*)outp)[((size_t)(b * HEADS + hh) * HDIM + d) * SEQ + ss] = __float2bfloat16(cv);
        } else if constexpr (MODE == 3) {
          ((float*)outp)[(size_t)m * EMB + n] = cv + bias[n] + resid[(size_t)m * EMB + n];
        } else if constexpr (MODE == 4) {
          ((bf16*)outp)[(size_t)m * FFDIM + n] = __float2bfloat16(gelu_f(cv + bias[n]));
        } else {
          ((float*)outp)[(size_t)m * EMB + n] = cv + bias[n] + resid[(size_t)m * EMB + n];
        }
      }
    }
  }
}

// ---- causal flash attention: swapped QK^T so softmax is lane-local-ish ----
// q,k: [64 bh][2048][64] bf16 (q pre-scaled by 0.125); vt: [64 bh][64][2048]
// ctx out: [8192][1024] bf16. 4 waves/block, 16 q-rows per wave, independent.
__global__ __launch_bounds__(256, 2) void attn_kernel(
    const bf16* __restrict__ q, const bf16* __restrict__ k,
    const bf16* __restrict__ vt, bf16* __restrict__ ctx) {
  const int bh = blockIdx.x, qt = blockIdx.y;
  const int tid = threadIdx.x;
  const int wave = tid >> 6, lane = tid & 63;
  const int lo = lane & 15, hi = lane >> 4;
  const int q0 = qt * 64 + wave * 16;
  const bf16* qp = q  + ((size_t)bh * SEQ + q0) * HDIM;
  const bf16* kp = k  + (size_t)bh * SEQ * HDIM;
  const bf16* vp = vt + (size_t)bh * HDIM * SEQ;

  short8 qf0 = *(const short8*)&qp[lo * HDIM + hi * 8];
  short8 qf1 = *(const short8*)&qp[lo * HDIM + 32 + hi * 8];

  float m_run = -1e30f, l_run = 0.0f;
  floatx4 o[4];
  #pragma unroll
  for (int df = 0; df < 4; df++)
    #pragma unroll
    for (int r = 0; r < 4; r++) o[df][r] = 0.0f;

  __shared__ __align__(16) bf16 Plds[4][16][32];

  const int nkt = (q0 + 16 + 31) >> 5;   // causal: keys <= q0+15
  for (int kt = 0; kt < nkt; ++kt) {
    const int k0 = kt * 32;
    // S'[key][q] = K * Q^T : D layout col=lane&15=q_rel, row=hi*4+r=key_rel
    floatx4 sfr[2];
    #pragma unroll
    for (int n = 0; n < 2; n++) {
      #pragma unroll
      for (int r = 0; r < 4; r++) sfr[n][r] = 0.0f;
      short8 kf0 = *(const short8*)&kp[(size_t)(k0 + n * 16 + lo) * HDIM + hi * 8];
      short8 kf1 = *(const short8*)&kp[(size_t)(k0 + n * 16 + lo) * HDIM + 32 + hi * 8];
      sfr[n] = __builtin_amdgcn_mfma_f32_16x16x32_bf16(kf0, qf0, sfr[n], 0, 0, 0);
      sfr[n] = __builtin_amdgcn_mfma_f32_16x16x32_bf16(kf1, qf1, sfr[n], 0, 0, 0);
    }
    const int qg = q0 + lo;
    float tmax = -1e30f;
    #pragma unroll
    for (int n = 0; n < 2; n++)
      #pragma unroll
      for (int r = 0; r < 4; r++) {
        int key = k0 + n * 16 + hi * 4 + r;
        float sv = sfr[n][r];
        if (key > qg) sv = -1e30f;           // causal mask (finite: no inf-inf)
        sfr[n][r] = sv;
        tmax = fmaxf(tmax, sv);
      }
    tmax = fmaxf(tmax, __shfl_xor(tmax, 16));
    tmax = fmaxf(tmax, __shfl_xor(tmax, 32));
    float m_new = fmaxf(m_run, tmax);
    float alpha = __expf(m_run - m_new);
    m_run = m_new;
    float psum = 0.0f;
    float pvv[2][4];
    #pragma unroll
    for (int n = 0; n < 2; n++)
      #pragma unroll
      for (int r = 0; r < 4; r++) {
        float p = __expf(sfr[n][r] - m_new);
        pvv[n][r] = p;
        psum += p;
      }
    psum += __shfl_xor(psum, 16);
    psum += __shfl_xor(psum, 32);
    l_run = l_run * alpha + psum;
    // P -> LDS in [q][key] layout (bf16), per-wave private slice
    #pragma unroll
    for (int n = 0; n < 2; n++) {
      ushort4 pk;
      pk.x = f2bu(pvv[n][0]); pk.y = f2bu(pvv[n][1]);
      pk.z = f2bu(pvv[n][2]); pk.w = f2bu(pvv[n][3]);
      *(ushort4*)&Plds[wave][lo][n * 16 + hi * 4] = pk;
    }
    asm volatile("s_waitcnt lgkmcnt(0)" ::: "memory");
    short8 pa = *(const short8*)&Plds[wave][lo][hi * 8];  // A-frag: row=q=lo, kk=key
    // rescale O rows by alpha (O rows live at q=hi*4+r; alpha lives at lane lo=q)
    float ar[4];
    #pragma unroll
    for (int r = 0; r < 4; r++) ar[r] = __shfl(alpha, hi * 4 + r);
    #pragma unroll
    for (int df = 0; df < 4; df++)
      #pragma unroll
      for (int r = 0; r < 4; r++) o[df][r] *= ar[r];
    #pragma unroll
    for (int df = 0; df < 4; df++) {
      short8 vf = *(const short8*)&vp[(size_t)(df * 16 + lo) * SEQ + k0 + hi * 8];
      o[df] = __builtin_amdgcn_mfma_f32_16x16x32_bf16(pa, vf, o[df], 0, 0, 0);
    }
  }
  float lr[4];
  #pragma unroll
  for (int r = 0; r < 4; r++) lr[r] = __shfl(l_run, hi * 4 + r);
  const int b = bh >> 4, hh = bh & 15;
  #pragma unroll
  for (int df = 0; df < 4; df++)
    #pragma unroll
    for (int r = 0; r < 4; r++) {
      int sglob = q0 + hi * 4 + r;
      ctx[(size_t)(b * SEQ + sglob) * EMB + hh * HDIM + df * 16 + lo] =
          __float2bfloat16(o[df][r] / lr[r]);
    }
}

extern "C" void kernel_launch(void* const* d_in, const int* in_sizes, int n_in,
                              void* d_out, int out_size, void* d_ws, size_t ws_size,
                              hipStream_t stream) {
  const float* x   = (const float*)d_in[0];
  const float* Wq  = (const float*)d_in[1];
  const float* Wk  = (const float*)d_in[2];
  const float* Wv  = (const float*)d_in[3];
  const float* Wo  = (const float*)d_in[4];
  const float* bo  = (const float*)d_in[5];
  const float* l1s = (const float*)d_in[6];
  const float* l1b = (const float*)d_in[7];
  const float* l2s = (const float*)d_in[8];
  const float* l2b = (const float*)d_in[9];
  const float* W1  = (const float*)d_in[10];
  const float* b1  = (const float*)d_in[11];
  const float* W2  = (const float*)d_in[12];
  const float* b2  = (const float*)d_in[13];
  float* out = (float*)d_out;

  // workspace layout (104 MB):
  // [0,64M): h(16M) q(16M) k(16M) v(16M); ctx reuses h; FF-act g reuses all 64M
  // [64M,80M): h2   [80M,104M): bf16 transposed weights
  char* ws = (char*)d_ws;
  bf16* hbuf   = (bf16*)(ws);
  bf16* qbuf   = (bf16*)(ws + ((size_t)16 << 20));
  bf16* kbuf   = (bf16*)(ws + ((size_t)32 << 20));
  bf16* vbuf   = (bf16*)(ws + ((size_t)48 << 20));
  bf16* ctxbuf = hbuf;
  bf16* gbuf   = (bf16*)(ws);
  bf16* h2buf  = (bf16*)(ws + ((size_t)64 << 20));
  bf16* WqT    = (bf16*)(ws + ((size_t)80 << 20));
  bf16* WkT    = WqT + (1u << 20);
  bf16* WvT    = WkT + (1u << 20);
  bf16* WoT    = WvT + (1u << 20);
  bf16* W1T    = WoT + (1u << 20);
  bf16* W2T    = W1T + (4u << 20);

  wconv_kernel<<<dim3(32, 32), 256, 0, stream>>>(Wq, WqT, 1024, 1024);
  wconv_kernel<<<dim3(32, 32), 256, 0, stream>>>(Wk, WkT, 1024, 1024);
  wconv_kernel<<<dim3(32, 32), 256, 0, stream>>>(Wv, WvT, 1024, 1024);
  wconv_kernel<<<dim3(32, 32), 256, 0, stream>>>(Wo, WoT, 1024, 1024);
  wconv_kernel<<<dim3(128, 32), 256, 0, stream>>>(W1, W1T, 1024, 4096);
  wconv_kernel<<<dim3(32, 128), 256, 0, stream>>>(W2, W2T, 4096, 1024);

  ln_kernel<<<8192, 256, 0, stream>>>(x, l1s, l1b, hbuf);

  gemm_kernel<1024, 1024, 0><<<dim3(64, 8), 256, 0, stream>>>(hbuf, WqT, nullptr, nullptr, qbuf);
  gemm_kernel<1024, 1024, 1><<<dim3(64, 8), 256, 0, stream>>>(hbuf, WkT, nullptr, nullptr, kbuf);
  gemm_kernel<1024, 1024, 2><<<dim3(64, 8), 256, 0, stream>>>(hbuf, WvT, nullptr, nullptr, vbuf);

  attn_kernel<<<dim3(64, 32), 256, 0, stream>>>(qbuf, kbuf, vbuf, ctxbuf);

  gemm_kernel<1024, 1024, 3><<<dim3(64, 8), 256, 0, stream>>>(ctxbuf, WoT, bo, x, (void*)out);
  ln_kernel<<<8192, 256, 0, stream>>>(out, l2s, l2b, h2buf);
  gemm_kernel<4096, 1024, 4><<<dim3(64, 32), 256, 0, stream>>>(h2buf, W1T, b1, nullptr, gbuf);
  gemm_kernel<1024, 4096, 5><<<dim3(64, 8), 256, 0, stream>>>(gbuf, W2T, b2, out, (void*)out);
}

// Round 2
// 521.943 us; speedup vs baseline: 1.3423x; 1.3423x over previous
//
#include <hip/hip_runtime.h>
#include <hip/hip_bf16.h>
#include <math.h>

typedef __hip_bfloat16 bf16;
typedef __attribute__((ext_vector_type(8))) short short8;
typedef __attribute__((ext_vector_type(4))) float floatx4;

#define EMB   1024
#define SEQ   2048
#define BATCH 4
#define M_TOK 8192
#define HEADS 16
#define HDIM  64
#define FFDIM 4096
#define KVB   64

typedef __attribute__((address_space(3))) void lds_t;
typedef __attribute__((address_space(1))) void glob_t;

static __device__ __forceinline__ void gll16(const bf16* g, bf16* l) {
  __builtin_amdgcn_global_load_lds((const glob_t*)g, (lds_t*)l, 16, 0, 0);
}

static __device__ __forceinline__ unsigned short f2bu(float f) {
  union { __hip_bfloat16 h; unsigned short u; } cv;
  cv.h = __float2bfloat16(f);
  return cv.u;
}

static __device__ __forceinline__ float gelu_f(float x) {
  float t = tanhf(0.7978845608028654f * (x + 0.044715f * x * x * x));
  return 0.5f * x * (1.0f + t);
}

// ---- weight convert + transpose: W fp32 [Kd][Nd] -> Wt bf16 [Nd][Kd] ----
__global__ __launch_bounds__(256) void wconv_kernel(const float* __restrict__ W,
                                                    bf16* __restrict__ Wt,
                                                    int Kd, int Nd) {
  __shared__ float tile[32][33];
  int n0 = blockIdx.x * 32, k0 = blockIdx.y * 32;
  int tx = threadIdx.x & 31, ty = threadIdx.x >> 5;
  #pragma unroll
  for (int j = 0; j < 32; j += 8)
    tile[ty + j][tx] = W[(size_t)(k0 + ty + j) * Nd + n0 + tx];
  __syncthreads();
  #pragma unroll
  for (int j = 0; j < 32; j += 8)
    Wt[(size_t)(n0 + ty + j) * Kd + k0 + tx] = __float2bfloat16(tile[tx][ty + j]);
}

// ---- LayerNorm (ddof=1): fp32 [8192][1024] -> bf16 ----
__global__ __launch_bounds__(256) void ln_kernel(const float* __restrict__ x,
                                                 const float* __restrict__ sc,
                                                 const float* __restrict__ bi,
                                                 bf16* __restrict__ out) {
  int row = blockIdx.x, tid = threadIdx.x;
  const float4* xr = (const float4*)(x + (size_t)row * EMB);
  float4 v = xr[tid];
  float s  = v.x + v.y + v.z + v.w;
  float s2 = v.x * v.x + v.y * v.y + v.z * v.z + v.w * v.w;
  #pragma unroll
  for (int off = 1; off < 64; off <<= 1) {
    s  += __shfl_xor(s, off);
    s2 += __shfl_xor(s2, off);
  }
  __shared__ float red[8];
  int wv = tid >> 6;
  if ((tid & 63) == 0) { red[wv] = s; red[4 + wv] = s2; }
  __syncthreads();
  s  = red[0] + red[1] + red[2] + red[3];
  s2 = red[4] + red[5] + red[6] + red[7];
  float mean = s * (1.0f / EMB);
  float var  = (s2 - (float)EMB * mean * mean) * (1.0f / (EMB - 1));
  float rstd = rsqrtf(var + 1e-5f);
  float4 scv = ((const float4*)sc)[tid];
  float4 biv = ((const float4*)bi)[tid];
  ushort4 o;
  o.x = f2bu((v.x - mean) * rstd * scv.x + biv.x);
  o.y = f2bu((v.y - mean) * rstd * scv.y + biv.y);
  o.z = f2bu((v.z - mean) * rstd * scv.z + biv.z);
  o.w = f2bu((v.w - mean) * rstd * scv.w + biv.w);
  ((ushort4*)(out + (size_t)row * EMB))[tid] = o;
}

// ---- GEMM: C[M=8192][Nd] = A[M][Kd] * Bt[Nd][Kd]^T, m97 structure ----
// MODE 3: fp32 out = C+bias+resid      MODE 4: bf16 out = gelu(C+bias)
// MODE 5: fp32 out = C+bias+resid      MODE 6: fused QKV (z: 0=q,1=k,2=vT)
template<int Nd, int Kd, int MODE>
__global__ __launch_bounds__(256, 2) void gemm_kernel(
    const bf16* __restrict__ A, const bf16* __restrict__ Bt,
    const float* __restrict__ bias, const float* __restrict__ resid,
    void* __restrict__ outp) {
  __shared__ __align__(16) bf16 As[128 * 32];
  __shared__ __align__(16) bf16 Bs[128 * 32];
  const int m0 = blockIdx.x * 128, n0 = blockIdx.y * 128;
  const int tid = threadIdx.x;
  const int lane = tid & 63, wave = tid >> 6;
  const int lo = lane & 15, hi = lane >> 4;
  const int wr = wave >> 1, wc = wave & 1;

  const bf16* Bt2 = Bt;
  if constexpr (MODE == 6) Bt2 = Bt + ((size_t)blockIdx.z << 20);

  floatx4 acc[4][4];
  #pragma unroll
  for (int i = 0; i < 4; i++)
    #pragma unroll
    for (int j = 0; j < 4; j++)
      #pragma unroll
      for (int r = 0; r < 4; r++) acc[i][j][r] = 0.0f;

  const bf16* Ab = A   + (size_t)m0 * Kd;
  const bf16* Bb = Bt2 + (size_t)n0 * Kd;

  for (int k0 = 0; k0 < Kd; k0 += 32) {
    #pragma unroll
    for (int s = 0; s < 2; ++s) {
      int c = tid + s * 256;   // chunk: row = c>>2, 16B sub-chunk = c&3
      gll16(Ab + (size_t)(c >> 2) * Kd + k0 + (c & 3) * 8, As + c * 8);
      gll16(Bb + (size_t)(c >> 2) * Kd + k0 + (c & 3) * 8, Bs + c * 8);
    }
    __syncthreads();
    short8 af[4], bfr[4];
    #pragma unroll
    for (int i = 0; i < 4; i++)
      af[i] = *(const short8*)&As[(wr * 64 + i * 16 + lo) * 32 + hi * 8];
    #pragma unroll
    for (int j = 0; j < 4; j++)
      bfr[j] = *(const short8*)&Bs[(wc * 64 + j * 16 + lo) * 32 + hi * 8];
    #pragma unroll
    for (int i = 0; i < 4; i++)
      #pragma unroll
      for (int j = 0; j < 4; j++)
        acc[i][j] = __builtin_amdgcn_mfma_f32_16x16x32_bf16(af[i], bfr[j], acc[i][j], 0, 0, 0);
    __syncthreads();
  }

  #pragma unroll
  for (int i = 0; i < 4; i++) {
    #pragma unroll
    for (int j = 0; j < 4; j++) {
      const int mb = m0 + wr * 64 + i * 16 + hi * 4;   // 4 consecutive m = mb+r
      const int n  = n0 + wc * 64 + j * 16 + lo;
      if constexpr (MODE == 6) {
        const int z = blockIdx.z;
        const int bb = mb >> 11, hhh = n >> 6, d = n & 63;
        bf16* ob = (bf16*)outp + ((size_t)z << 23);
        if (z == 2) {
          // v transposed [b,h,d,s]: pack 4 consecutive s into one 8B store
          ushort4 pk;
          pk.x = f2bu(acc[i][j][0]); pk.y = f2bu(acc[i][j][1]);
          pk.z = f2bu(acc[i][j][2]); pk.w = f2bu(acc[i][j][3]);
          *(ushort4*)&ob[((size_t)(bb * HEADS + hhh) * HDIM + d) * SEQ + (mb & 2047)] = pk;
        } else {
          const float sc = (z == 0) ? 0.125f : 1.0f;   // fold softmax scale into q
          #pragma unroll
          for (int r = 0; r < 4; r++) {
            const int ss = (mb + r) & 2047;
            ob[((size_t)(bb * HEADS + hhh) * SEQ + ss) * HDIM + d] =
                __float2bfloat16(acc[i][j][r] * sc);
          }
        }
      } else if constexpr (MODE == 3 || MODE == 5) {
        #pragma unroll
        for (int r = 0; r < 4; r++) {
          const int m = mb + r;
          ((float*)outp)[(size_t)m * EMB + n] =
              acc[i][j][r] + bias[n] + resid[(size_t)m * EMB + n];
        }
      } else if constexpr (MODE == 4) {
        #pragma unroll
        for (int r = 0; r < 4; r++)
          ((bf16*)outp)[(size_t)(mb + r) * FFDIM + n] =
              __float2bfloat16(gelu_f(acc[i][j][r] + bias[n]));
      }
    }
  }
}

// ---- causal flash attention, staged + double-buffered ----
// Block: 128 q-rows (4 waves x 32 q), KV tile = 64 keys shared via LDS.
// q,k: [64 bh][2048][64] bf16 (q pre-scaled); vt: [64 bh][64][2048]
// K/V LDS rows are 128B: XOR-swizzle byte^=((row&7)<<4) via pre-swizzled
// global source (linear gll dest) + swizzled ds_read (rule 21).
__global__ __launch_bounds__(256, 2) void attn_kernel(
    const bf16* __restrict__ q, const bf16* __restrict__ k,
    const bf16* __restrict__ vt, bf16* __restrict__ ctx) {
  __shared__ __align__(16) char KVs[2][2][64 * 128];  // [buf][K|V][row 64][128B]
  __shared__ __align__(16) char Pls[4][4096];         // per-wave P [32][64] bf16, swz
  const int bh = blockIdx.x, qt = blockIdx.y;
  const int tid = threadIdx.x;
  const int wave = tid >> 6, lane = tid & 63;
  const int lo = lane & 15, hi = lane >> 4;
  const int lo7 = lo & 7;
  const int q0 = qt * 128;
  const int q0w = q0 + wave * 32;
  const int qmax = q0w + 31;

  const bf16* qp = q  + ((size_t)bh * SEQ + q0w) * HDIM;
  const bf16* kp = k  + (size_t)bh * SEQ * HDIM;
  const bf16* vp = vt + (size_t)bh * HDIM * SEQ;

  // Q fragments (B-operand: col=q=lo, elements d=kk*32+hi*8..+8)
  short8 qf[2][2];
  #pragma unroll
  for (int m = 0; m < 2; m++)
    #pragma unroll
    for (int kk = 0; kk < 2; kk++)
      qf[m][kk] = *(const short8*)&qp[(size_t)(m * 16 + lo) * HDIM + kk * 32 + hi * 8];

  float m_run[2] = {-1e30f, -1e30f};
  float l_run[2] = {0.0f, 0.0f};
  floatx4 o[4][2];
  #pragma unroll
  for (int df = 0; df < 4; df++)
    #pragma unroll
    for (int m = 0; m < 2; m++)
      #pragma unroll
      for (int r = 0; r < 4; r++) o[df][m][r] = 0.0f;

  const int nt = 2 * qt + 2;   // tiles cover keys [0, q0+128)

  // staging chunks: 512 x 16B per matrix; this thread's two chunks.
  // dest byte = c*16 (linear); row = c>>3; src 16B-col = (c&7) ^ (row&7).
  const int c0 = tid, c1 = tid + 256;
  const int r0 = c0 >> 3, s0 = (c0 & 7) ^ (r0 & 7);
  const int r1 = c1 >> 3, s1 = (c1 & 7) ^ (r1 & 7);

  // prologue: stage tile 0
  gll16(kp + (size_t)r0 * HDIM + s0 * 8, (bf16*)&KVs[0][0][c0 * 16]);
  gll16(vp + (size_t)r0 * SEQ + s0 * 8,  (bf16*)&KVs[0][1][c0 * 16]);
  gll16(kp + (size_t)r1 * HDIM + s1 * 8, (bf16*)&KVs[0][0][c1 * 16]);
  gll16(vp + (size_t)r1 * SEQ + s1 * 8,  (bf16*)&KVs[0][1][c1 * 16]);

  for (int t = 0; t < nt; ++t) {
    const int buf = t & 1;
    const int k0 = t * KVB;
    if (t + 1 < nt) {   // issue next tile's stage, then drain only the previous
      const int kn = k0 + KVB;
      gll16(kp + (size_t)(kn + r0) * HDIM + s0 * 8, (bf16*)&KVs[buf ^ 1][0][c0 * 16]);
      gll16(vp + (size_t)r0 * SEQ + kn + s0 * 8,    (bf16*)&KVs[buf ^ 1][1][c0 * 16]);
      gll16(kp + (size_t)(kn + r1) * HDIM + s1 * 8, (bf16*)&KVs[buf ^ 1][0][c1 * 16]);
      gll16(vp + (size_t)r1 * SEQ + kn + s1 * 8,    (bf16*)&KVs[buf ^ 1][1][c1 * 16]);
      asm volatile("s_waitcnt vmcnt(4)" ::: "memory");
    } else {
      asm volatile("s_waitcnt vmcnt(0)" ::: "memory");
    }
    __builtin_amdgcn_s_barrier();
    __builtin_amdgcn_sched_barrier(0);

    if (k0 <= qmax) {            // wave-uniform causal skip (barriers outside)
      const char* Kb = KVs[buf][0];
      const char* Vb = KVs[buf][1];
      // QK^T: S'[key][q], A=K rows (key=kf*16+lo), B=Q
      floatx4 sfr[4][2];
      #pragma unroll
      for (int kf = 0; kf < 4; kf++) {
        const int rowb = (kf * 16 + lo) * 128;
        short8 kf0 = *(const short8*)(Kb + rowb + (( 0 + hi * 16) ^ (lo7 << 4)));
        short8 kf1 = *(const short8*)(Kb + rowb + ((64 + hi * 16) ^ (lo7 << 4)));
        #pragma unroll
        for (int m = 0; m < 2; m++) {
          floatx4 z = {0.0f, 0.0f, 0.0f, 0.0f};
          z = __builtin_amdgcn_mfma_f32_16x16x32_bf16(kf0, qf[m][0], z, 0, 0, 0);
          z = __builtin_amdgcn_mfma_f32_16x16x32_bf16(kf1, qf[m][1], z, 0, 0, 0);
          sfr[kf][m] = z;
        }
      }
      // causal mask, only on boundary tiles
      if (k0 + KVB - 1 > q0w) {
        #pragma unroll
        for (int m = 0; m < 2; m++) {
          const int qg = q0w + m * 16 + lo;
          #pragma unroll
          for (int kf = 0; kf < 4; kf++)
            #pragma unroll
            for (int r = 0; r < 4; r++) {
              const int key = k0 + kf * 16 + hi * 4 + r;
              if (key > qg) sfr[kf][m][r] = -1e30f;
            }
        }
      }
      // online softmax per q-frag m; P -> LDS (swizzled, per-wave slice)
      float alpha[2];
      #pragma unroll
      for (int m = 0; m < 2; m++) {
        float tmax = -1e30f;
        #pragma unroll
        for (int kf = 0; kf < 4; kf++)
          #pragma unroll
          for (int r = 0; r < 4; r++) tmax = fmaxf(tmax, sfr[kf][m][r]);
        tmax = fmaxf(tmax, __shfl_xor(tmax, 16));
        tmax = fmaxf(tmax, __shfl_xor(tmax, 32));
        const float mn = fmaxf(m_run[m], tmax);
        alpha[m] = __expf(m_run[m] - mn);
        m_run[m] = mn;
        float ps = 0.0f;
        const int prow = (m * 16 + lo) * 128;
        #pragma unroll
        for (int kf = 0; kf < 4; kf++) {
          float p0 = __expf(sfr[kf][m][0] - mn);
          float p1 = __expf(sfr[kf][m][1] - mn);
          float p2 = __expf(sfr[kf][m][2] - mn);
          float p3 = __expf(sfr[kf][m][3] - mn);
          ps += (p0 + p1) + (p2 + p3);
          ushort4 pk;
          pk.x = f2bu(p0); pk.y = f2bu(p1); pk.z = f2bu(p2); pk.w = f2bu(p3);
          *(ushort4*)(Pls[wave] + prow + ((kf * 32 + hi * 8) ^ (lo7 << 4))) = pk;
        }
        ps += __shfl_xor(ps, 16);
        ps += __shfl_xor(ps, 32);
        l_run[m] = l_run[m] * alpha[m] + ps;
      }
      asm volatile("s_waitcnt lgkmcnt(0)" ::: "memory");
      __builtin_amdgcn_sched_barrier(0);   // rule 18: pin reads after the wait
      short8 pa[2][2];
      #pragma unroll
      for (int m = 0; m < 2; m++)
        #pragma unroll
        for (int kk2 = 0; kk2 < 2; kk2++)
          pa[m][kk2] = *(const short8*)(Pls[wave] + (m * 16 + lo) * 128 +
                                        ((kk2 * 64 + hi * 16) ^ (lo7 << 4)));
      // rescale O by alpha (O rows are q=hi*4+r; alpha lives at lane lo=q)
      float ar[2][4];
      #pragma unroll
      for (int m = 0; m < 2; m++)
        #pragma unroll
        for (int r = 0; r < 4; r++) ar[m][r] = __shfl(alpha[m], hi * 4 + r);
      #pragma unroll
      for (int df = 0; df < 4; df++)
        #pragma unroll
        for (int m = 0; m < 2; m++)
          #pragma unroll
          for (int r = 0; r < 4; r++) o[df][m][r] *= ar[m][r];
      // PV: B=V^T rows d (Vs[d][key]), elements key
      #pragma unroll
      for (int df = 0; df < 4; df++) {
        const int rowb = (df * 16 + lo) * 128;
        short8 vf0 = *(const short8*)(Vb + rowb + (( 0 + hi * 16) ^ (lo7 << 4)));
        short8 vf1 = *(const short8*)(Vb + rowb + ((64 + hi * 16) ^ (lo7 << 4)));
        #pragma unroll
        for (int m = 0; m < 2; m++) {
          o[df][m] = __builtin_amdgcn_mfma_f32_16x16x32_bf16(pa[m][0], vf0, o[df][m], 0, 0, 0);
          o[df][m] = __builtin_amdgcn_mfma_f32_16x16x32_bf16(pa[m][1], vf1, o[df][m], 0, 0, 0);
        }
      }
    }
    __builtin_amdgcn_s_barrier();        // compute done; next staging is safe
    __builtin_amdgcn_sched_barrier(0);
  }

  const int b = bh >> 4, hh = bh & 15;
  #pragma unroll
  for (int m = 0; m < 2; m++) {
    float lr[4];
    #pragma unroll
    for (int r = 0; r < 4; r++) lr[r] = __shfl(l_run[m], hi * 4 + r);
    #pragma unroll
    for (int df = 0; df < 4; df++)
      #pragma unroll
      for (int r = 0; r < 4; r++) {
        const int srow = q0w + m * 16 + hi * 4 + r;
        ctx[((size_t)(b * SEQ + srow)) * EMB + hh * HDIM + df * 16 + lo] =
            __float2bfloat16(o[df][m][r] / lr[r]);
      }
  }
}

extern "C" void kernel_launch(void* const* d_in, const int* in_sizes, int n_in,
                              void* d_out, int out_size, void* d_ws, size_t ws_size,
                              hipStream_t stream) {
  const float* x   = (const float*)d_in[0];
  const float* Wq  = (const float*)d_in[1];
  const float* Wk  = (const float*)d_in[2];
  const float* Wv  = (const float*)d_in[3];
  const float* Wo  = (const float*)d_in[4];
  const float* bo  = (const float*)d_in[5];
  const float* l1s = (const float*)d_in[6];
  const float* l1b = (const float*)d_in[7];
  const float* l2s = (const float*)d_in[8];
  const float* l2b = (const float*)d_in[9];
  const float* W1  = (const float*)d_in[10];
  const float* b1  = (const float*)d_in[11];
  const float* W2  = (const float*)d_in[12];
  const float* b2  = (const float*)d_in[13];
  float* out = (float*)d_out;

  // workspace layout (104 MB):
  // [0,64M): h(16M) q(16M) k(16M) v(16M); ctx reuses h; FF-act g reuses all 64M
  // [64M,80M): h2   [80M,104M): bf16 transposed weights (WqT,WkT,WvT contiguous)
  char* ws = (char*)d_ws;
  bf16* hbuf   = (bf16*)(ws);
  bf16* qbuf   = (bf16*)(ws + ((size_t)16 << 20));
  bf16* kbuf   = (bf16*)(ws + ((size_t)32 << 20));
  bf16* vbuf   = (bf16*)(ws + ((size_t)48 << 20));
  bf16* ctxbuf = hbuf;
  bf16* gbuf   = (bf16*)(ws);
  bf16* h2buf  = (bf16*)(ws + ((size_t)64 << 20));
  bf16* WqT    = (bf16*)(ws + ((size_t)80 << 20));
  bf16* WkT    = WqT + (1u << 20);
  bf16* WvT    = WkT + (1u << 20);
  bf16* WoT    = WvT + (1u << 20);
  bf16* W1T    = WoT + (1u << 20);
  bf16* W2T    = W1T + (4u << 20);

  wconv_kernel<<<dim3(32, 32), 256, 0, stream>>>(Wq, WqT, 1024, 1024);
  wconv_kernel<<<dim3(32, 32), 256, 0, stream>>>(Wk, WkT, 1024, 1024);
  wconv_kernel<<<dim3(32, 32), 256, 0, stream>>>(Wv, WvT, 1024, 1024);
  wconv_kernel<<<dim3(32, 32), 256, 0, stream>>>(Wo, WoT, 1024, 1024);
  wconv_kernel<<<dim3(128, 32), 256, 0, stream>>>(W1, W1T, 1024, 4096);
  wconv_kernel<<<dim3(32, 128), 256, 0, stream>>>(W2, W2T, 4096, 1024);

  ln_kernel<<<8192, 256, 0, stream>>>(x, l1s, l1b, hbuf);

  // fused QKV: z=0 -> q (scaled), z=1 -> k, z=2 -> v transposed
  gemm_kernel<1024, 1024, 6><<<dim3(64, 8, 3), 256, 0, stream>>>(hbuf, WqT, nullptr, nullptr, qbuf);

  attn_kernel<<<dim3(64, 16), 256, 0, stream>>>(qbuf, kbuf, vbuf, ctxbuf);

  gemm_kernel<1024, 1024, 3><<<dim3(64, 8), 256, 0, stream>>>(ctxbuf, WoT, bo, x, (void*)out);
  ln_kernel<<<8192, 256, 0, stream>>>(out, l2s, l2b, h2buf);
  gemm_kernel<4096, 1024, 4><<<dim3(64, 32), 256, 0, stream>>>(h2buf, W1T, b1, nullptr, gbuf);
  gemm_kernel<1024, 4096, 5><<<dim3(64, 8), 256, 0, stream>>>(gbuf, W2T, b2, out, (void*)out);
}